// Round 5
// baseline (262.226 us; speedup 1.0000x reference)
//
#include <hip/hip_runtime.h>
#include <math.h>

#define NTOK 8192   // B*S = 4*2048
#define HDIM 2048
#define FDIM 8192
#define NEXP 8

typedef float f32x4 __attribute__((ext_vector_type(4)));

// ---- router: logits = x@Wr + br, softmax, top-2; also zeroes tok and seeds ebar ----
__global__ __launch_bounds__(256) void router_kernel(const float* __restrict__ x,
                                                     const float* __restrict__ Wr,
                                                     const float* __restrict__ br,
                                                     const float* __restrict__ b2,
                                                     float* __restrict__ G,
                                                     int* __restrict__ sel,
                                                     float* __restrict__ tok,
                                                     float* __restrict__ ebar) {
  {
    const int idx = blockIdx.x * 256 + threadIdx.x;
    if (idx < (16 * HDIM) / 4) {
      *(float4*)(tok + idx * 4) = make_float4(0.f, 0.f, 0.f, 0.f);
    } else if (idx < (16 * HDIM) / 4 + 1024) {  // seed ebar[2][2048] with sum_e b2
      const int j = idx - (16 * HDIM) / 4;
      const int h = (j & 511) << 2;
      float4 s = make_float4(0.f, 0.f, 0.f, 0.f);
#pragma unroll
      for (int e = 0; e < 8; ++e) {
        float4 b = *(const float4*)(b2 + e * HDIM + h);
        s.x += b.x; s.y += b.y; s.z += b.z; s.w += b.w;
      }
      *(float4*)(ebar + (j >> 9) * HDIM + h) = s;
    }
  }
  const int wave = threadIdx.x >> 6;
  const int lane = threadIdx.x & 63;
  const int n0 = (blockIdx.x * 4 + wave) * 4;

  float acc[4][8];
#pragma unroll
  for (int t = 0; t < 4; ++t)
#pragma unroll
    for (int e = 0; e < 8; ++e) acc[t][e] = 0.f;

#pragma unroll 4
  for (int j = 0; j < 32; ++j) {
    const int h = lane + (j << 6);
    float4 wa = *(const float4*)(Wr + h * 8);
    float4 wb = *(const float4*)(Wr + h * 8 + 4);
    float w[8] = {wa.x, wa.y, wa.z, wa.w, wb.x, wb.y, wb.z, wb.w};
#pragma unroll
    for (int t = 0; t < 4; ++t) {
      float xv = x[(size_t)(n0 + t) * HDIM + h];
#pragma unroll
      for (int e = 0; e < 8; ++e) acc[t][e] = fmaf(xv, w[e], acc[t][e]);
    }
  }

#pragma unroll
  for (int t = 0; t < 4; ++t)
#pragma unroll
    for (int e = 0; e < 8; ++e) {
      float v = acc[t][e];
      v += __shfl_xor(v, 1, 64);
      v += __shfl_xor(v, 2, 64);
      v += __shfl_xor(v, 4, 64);
      v += __shfl_xor(v, 8, 64);
      v += __shfl_xor(v, 16, 64);
      v += __shfl_xor(v, 32, 64);
      acc[t][e] = v;
    }

  if (lane == 0) {
    float brv[8];
#pragma unroll
    for (int e = 0; e < 8; ++e) brv[e] = br[e];
#pragma unroll
    for (int t = 0; t < 4; ++t) {
      float l[8];
#pragma unroll
      for (int e = 0; e < 8; ++e) l[e] = acc[t][e] + brv[e];
      float m = l[0];
#pragma unroll
      for (int e = 1; e < 8; ++e) m = fmaxf(m, l[e]);
      float s = 0.f;
#pragma unroll
      for (int e = 0; e < 8; ++e) s += expf(l[e] - m);
      float best = l[0], second = -3.4e38f;
      int bi = 0, si = 0;
#pragma unroll
      for (int e = 1; e < 8; ++e) {
        float v = l[e];
        if (v > best) { second = best; si = bi; best = v; bi = e; }
        else if (v > second) { second = v; si = e; }
      }
      const int n = n0 + t;
      const float inv = 1.f / s;
      G[n * 2 + 0] = expf(best - m) * inv;
      G[n * 2 + 1] = expf(second - m) * inv;
      sel[n * 2 + 0] = bi;
      sel[n * 2 + 1] = si;
    }
  }
}

// ---- tok[e,k,h] = sum over tokens routed to (e,k) of x[n,h]; float2-vectorized ----
__global__ __launch_bounds__(256) void tok_kernel(const float* __restrict__ x,
                                                  const int* __restrict__ sel,
                                                  float* __restrict__ tok) {
  __shared__ float2 part[16][256];
  __shared__ int sidx[256];
  const int tid = threadIdx.x;
  const int h0 = blockIdx.x << 9;  // 4 chunks x 512 h
  const int n0 = blockIdx.y << 7;  // 64 chunks x 128 tokens
#pragma unroll
  for (int s = 0; s < 16; ++s) part[s][tid] = make_float2(0.f, 0.f);
  sidx[tid] = sel[(n0 << 1) + tid];
  __syncthreads();
#pragma unroll 8
  for (int i = 0; i < 128; ++i) {
    float2 v = *(const float2*)(x + (size_t)(n0 + i) * HDIM + h0 + tid * 2);
    int s0 = sidx[2 * i] << 1;            // (e0, k=0)
    int s1 = (sidx[2 * i + 1] << 1) + 1;  // (e1, k=1)
    part[s0][tid].x += v.x; part[s0][tid].y += v.y;
    part[s1][tid].x += v.x; part[s1][tid].y += v.y;
  }
#pragma unroll
  for (int s = 0; s < 16; ++s) {
    atomicAdd(&tok[s * HDIM + h0 + tid * 2 + 0], part[s][tid].x);
    atomicAdd(&tok[s * HDIM + h0 + tid * 2 + 1], part[s][tid].y);
  }
}

// ---- up-proj partials: up_part[e][hc][k][f], 128 h per block ----
__global__ __launch_bounds__(256) void up_kernel(const float* __restrict__ tok,
                                                 const float* __restrict__ W1,
                                                 float* __restrict__ up_part) {
  const int e = blockIdx.z;
  const int hc = blockIdx.y;
  const int tid = threadIdx.x;
  const int f = (blockIdx.x << 10) + (tid << 2);
  const int h0 = hc << 7;
  __shared__ float t0s[128], t1s[128];
  if (tid < 128) t0s[tid] = tok[(e * 2 + 0) * HDIM + h0 + tid];
  else           t1s[tid - 128] = tok[(e * 2 + 1) * HDIM + h0 + (tid - 128)];
  __syncthreads();
  const float* Wp = W1 + ((size_t)e * HDIM + h0) * FDIM + f;
  float4 a0 = make_float4(0.f, 0.f, 0.f, 0.f), a1 = make_float4(0.f, 0.f, 0.f, 0.f);
#pragma unroll 16
  for (int hh = 0; hh < 128; ++hh) {
    f32x4 w = __builtin_nontemporal_load(reinterpret_cast<const f32x4*>(Wp + (size_t)hh * FDIM));
    float t0 = t0s[hh], t1 = t1s[hh];
    a0.x = fmaf(t0, w.x, a0.x); a0.y = fmaf(t0, w.y, a0.y);
    a0.z = fmaf(t0, w.z, a0.z); a0.w = fmaf(t0, w.w, a0.w);
    a1.x = fmaf(t1, w.x, a1.x); a1.y = fmaf(t1, w.y, a1.y);
    a1.z = fmaf(t1, w.z, a1.z); a1.w = fmaf(t1, w.w, a1.w);
  }
  float* p0 = up_part + ((size_t)((e * 16 + hc) * 2 + 0) * FDIM) + f;
  float* p1 = up_part + ((size_t)((e * 16 + hc) * 2 + 1) * FDIM) + f;
  *(float4*)p0 = a0;
  *(float4*)p1 = a1;
}

// ---- down-proj with fused GELU prologue: down_part[e][fc][k][h], fc=64 ----
// prologue: mid[e][k][f-slice] = gelu(sum_hc up_part + b1), computed in-block into LDS.
__global__ __launch_bounds__(256) void down_kernel(const float* __restrict__ up_part,
                                                   const float* __restrict__ b1,
                                                   const float* __restrict__ W2,
                                                   float* __restrict__ down_part) {
  const int e = blockIdx.z;
  const int fc = blockIdx.x;           // 0..63
  const int tid = threadIdx.x;
  const int f0 = fc << 7;              // 128 f rows per block
  const int h = (blockIdx.y << 10) + (tid << 2);
  __shared__ float ms[2][128];
  {
    const int k = tid >> 7;            // 0 or 1
    const int fl = tid & 127;
    float acc = 0.f;
#pragma unroll
    for (int hc = 0; hc < 16; ++hc)
      acc += up_part[(size_t)((e * 16 + hc) * 2 + k) * FDIM + f0 + fl];
    acc += b1[e * FDIM + f0 + fl];
    ms[k][fl] = 0.5f * acc * (1.f + erff(acc * 0.70710678118654752f));
  }
  __syncthreads();
  const float* Wp = W2 + ((size_t)e * FDIM + f0) * HDIM + h;
  float4 a0 = make_float4(0.f, 0.f, 0.f, 0.f), a1 = make_float4(0.f, 0.f, 0.f, 0.f);
#pragma unroll 16
  for (int ff = 0; ff < 128; ++ff) {
    f32x4 w = __builtin_nontemporal_load(reinterpret_cast<const f32x4*>(Wp + (size_t)ff * HDIM));
    float m0 = ms[0][ff], m1 = ms[1][ff];
    a0.x = fmaf(m0, w.x, a0.x); a0.y = fmaf(m0, w.y, a0.y);
    a0.z = fmaf(m0, w.z, a0.z); a0.w = fmaf(m0, w.w, a0.w);
    a1.x = fmaf(m1, w.x, a1.x); a1.y = fmaf(m1, w.y, a1.y);
    a1.z = fmaf(m1, w.z, a1.z); a1.w = fmaf(m1, w.w, a1.w);
  }
  float* p0 = down_part + ((size_t)((e * 64 + fc) * 2 + 0) * HDIM) + h;
  float* p1 = down_part + ((size_t)((e * 64 + fc) * 2 + 1) * HDIM) + h;
  *(float4*)p0 = a0;
  *(float4*)p1 = a1;
}

// ---- ebar += coalesced reduction of down_part (512 slices); 64 blocks x 8 combos ----
__global__ __launch_bounds__(256) void ebar_reduce_kernel(const float* __restrict__ down_part,
                                                          float* __restrict__ ebar) {
  const int tid = threadIdx.x;
  const int c0 = blockIdx.x * 8;  // combos c = (e*64+fc) in [0,512)
  float4 acc[2][2];               // [k][h-round: h4 = tid, tid+256]
#pragma unroll
  for (int k = 0; k < 2; ++k)
#pragma unroll
    for (int r = 0; r < 2; ++r) acc[k][r] = make_float4(0.f, 0.f, 0.f, 0.f);
#pragma unroll
  for (int j = 0; j < 8; ++j) {
    const int c = c0 + j;
#pragma unroll
    for (int k = 0; k < 2; ++k) {
      const float* base = down_part + (size_t)(c * 2 + k) * HDIM;
#pragma unroll
      for (int r = 0; r < 2; ++r) {
        float4 v = *(const float4*)(base + ((r << 8) + tid) * 4);
        acc[k][r].x += v.x; acc[k][r].y += v.y; acc[k][r].z += v.z; acc[k][r].w += v.w;
      }
    }
  }
#pragma unroll
  for (int k = 0; k < 2; ++k)
#pragma unroll
    for (int r = 0; r < 2; ++r) {
      float* dst = ebar + k * HDIM + ((r << 8) + tid) * 4;
      atomicAdd(dst + 0, acc[k][r].x);
      atomicAdd(dst + 1, acc[k][r].y);
      atomicAdd(dst + 2, acc[k][r].z);
      atomicAdd(dst + 3, acc[k][r].w);
    }
}

// ---- combine: y[n,h] = G[n,0]*ebar[0,h] + G[n,1]*ebar[1,h] ----
__global__ __launch_bounds__(256) void combine_kernel(const float* __restrict__ G,
                                                      const float* __restrict__ ebar,
                                                      float* __restrict__ y) {
  const int i4 = blockIdx.x * 256 + threadIdx.x;  // NTOK*HDIM/4 = 4194304 total
  const int n = i4 >> 9;
  const int h = (i4 & 511) << 2;
  const float g0 = G[n * 2 + 0], g1 = G[n * 2 + 1];
  float4 e0 = *(const float4*)(ebar + h);
  float4 e1 = *(const float4*)(ebar + HDIM + h);
  f32x4 r;
  r.x = fmaf(g0, e0.x, g1 * e1.x);
  r.y = fmaf(g0, e0.y, g1 * e1.y);
  r.z = fmaf(g0, e0.z, g1 * e1.z);
  r.w = fmaf(g0, e0.w, g1 * e1.w);
  __builtin_nontemporal_store(r, reinterpret_cast<f32x4*>(y + ((size_t)n << 11) + h));
}

extern "C" void kernel_launch(void* const* d_in, const int* in_sizes, int n_in,
                              void* d_out, int out_size, void* d_ws, size_t ws_size,
                              hipStream_t stream) {
  const float* x  = (const float*)d_in[0];
  const float* Wr = (const float*)d_in[1];
  const float* br = (const float*)d_in[2];
  const float* W1 = (const float*)d_in[3];
  const float* b1 = (const float*)d_in[4];
  const float* W2 = (const float*)d_in[5];
  const float* b2 = (const float*)d_in[6];
  float* y = (float*)d_out;

  char* ws = (char*)d_ws;
  float* G         = (float*)(ws);               // 64 KB
  int*   sel       = (int*)(ws + (64 << 10));    // 64 KB
  float* tok       = (float*)(ws + (128 << 10)); // 128 KB
  float* ebar      = (float*)(ws + (256 << 10)); // 16 KB
  float* up_part   = (float*)(ws + (512 << 10));             // 8 MB: [8][16][2][8192]
  float* down_part = (float*)(ws + (512 << 10) + (8 << 20)); // 8 MB: [8][64][2][2048]

  router_kernel<<<512, 256, 0, stream>>>(x, Wr, br, b2, G, sel, tok, ebar);
  tok_kernel<<<dim3(4, 64), 256, 0, stream>>>(x, sel, tok);
  up_kernel<<<dim3(8, 16, 8), 256, 0, stream>>>(tok, W1, up_part);
  down_kernel<<<dim3(64, 2, 8), 256, 0, stream>>>(up_part, b1, W2, down_part);
  ebar_reduce_kernel<<<64, 256, 0, stream>>>(down_part, ebar);
  combine_kernel<<<16384, 256, 0, stream>>>(G, ebar, y);
}

// Round 6
// 258.725 us; speedup vs baseline: 1.0135x; 1.0135x over previous
//
#include <hip/hip_runtime.h>
#include <math.h>

#define NTOK 8192   // B*S = 4*2048
#define HDIM 2048
#define FDIM 8192
#define NEXP 8

typedef float f32x4 __attribute__((ext_vector_type(4)));

// ---- router: logits = x@Wr + br, softmax, top-2; also zeroes tok and seeds ebar ----
__global__ __launch_bounds__(256) void router_kernel(const float* __restrict__ x,
                                                     const float* __restrict__ Wr,
                                                     const float* __restrict__ br,
                                                     const float* __restrict__ b2,
                                                     float* __restrict__ G,
                                                     int* __restrict__ sel,
                                                     float* __restrict__ tok,
                                                     float* __restrict__ ebar) {
  {
    const int idx = blockIdx.x * 256 + threadIdx.x;
    if (idx < (16 * HDIM) / 4) {
      *(float4*)(tok + idx * 4) = make_float4(0.f, 0.f, 0.f, 0.f);
    } else if (idx < (16 * HDIM) / 4 + 1024) {  // seed ebar[2][2048] with sum_e b2
      const int j = idx - (16 * HDIM) / 4;
      const int h = (j & 511) << 2;
      float4 s = make_float4(0.f, 0.f, 0.f, 0.f);
#pragma unroll
      for (int e = 0; e < 8; ++e) {
        float4 b = *(const float4*)(b2 + e * HDIM + h);
        s.x += b.x; s.y += b.y; s.z += b.z; s.w += b.w;
      }
      *(float4*)(ebar + (j >> 9) * HDIM + h) = s;
    }
  }
  const int wave = threadIdx.x >> 6;
  const int lane = threadIdx.x & 63;
  const int n0 = (blockIdx.x * 4 + wave) * 4;

  float acc[4][8];
#pragma unroll
  for (int t = 0; t < 4; ++t)
#pragma unroll
    for (int e = 0; e < 8; ++e) acc[t][e] = 0.f;

#pragma unroll 4
  for (int j = 0; j < 32; ++j) {
    const int h = lane + (j << 6);
    float4 wa = *(const float4*)(Wr + h * 8);
    float4 wb = *(const float4*)(Wr + h * 8 + 4);
    float w[8] = {wa.x, wa.y, wa.z, wa.w, wb.x, wb.y, wb.z, wb.w};
#pragma unroll
    for (int t = 0; t < 4; ++t) {
      float xv = x[(size_t)(n0 + t) * HDIM + h];
#pragma unroll
      for (int e = 0; e < 8; ++e) acc[t][e] = fmaf(xv, w[e], acc[t][e]);
    }
  }

#pragma unroll
  for (int t = 0; t < 4; ++t)
#pragma unroll
    for (int e = 0; e < 8; ++e) {
      float v = acc[t][e];
      v += __shfl_xor(v, 1, 64);
      v += __shfl_xor(v, 2, 64);
      v += __shfl_xor(v, 4, 64);
      v += __shfl_xor(v, 8, 64);
      v += __shfl_xor(v, 16, 64);
      v += __shfl_xor(v, 32, 64);
      acc[t][e] = v;
    }

  if (lane == 0) {
    float brv[8];
#pragma unroll
    for (int e = 0; e < 8; ++e) brv[e] = br[e];
#pragma unroll
    for (int t = 0; t < 4; ++t) {
      float l[8];
#pragma unroll
      for (int e = 0; e < 8; ++e) l[e] = acc[t][e] + brv[e];
      float m = l[0];
#pragma unroll
      for (int e = 1; e < 8; ++e) m = fmaxf(m, l[e]);
      float s = 0.f;
#pragma unroll
      for (int e = 0; e < 8; ++e) s += expf(l[e] - m);
      float best = l[0], second = -3.4e38f;
      int bi = 0, si = 0;
#pragma unroll
      for (int e = 1; e < 8; ++e) {
        float v = l[e];
        if (v > best) { second = best; si = bi; best = v; bi = e; }
        else if (v > second) { second = v; si = e; }
      }
      const int n = n0 + t;
      const float inv = 1.f / s;
      G[n * 2 + 0] = expf(best - m) * inv;
      G[n * 2 + 1] = expf(second - m) * inv;
      sel[n * 2 + 0] = bi;
      sel[n * 2 + 1] = si;
    }
  }
}

// ---- tok[e,k,h] = sum over tokens routed to (e,k) of x[n,h]; float2-vectorized ----
__global__ __launch_bounds__(256) void tok_kernel(const float* __restrict__ x,
                                                  const int* __restrict__ sel,
                                                  float* __restrict__ tok) {
  __shared__ float2 part[16][256];
  __shared__ int sidx[256];
  const int tid = threadIdx.x;
  const int h0 = blockIdx.x << 9;  // 4 chunks x 512 h
  const int n0 = blockIdx.y << 7;  // 64 chunks x 128 tokens
#pragma unroll
  for (int s = 0; s < 16; ++s) part[s][tid] = make_float2(0.f, 0.f);
  sidx[tid] = sel[(n0 << 1) + tid];
  __syncthreads();
#pragma unroll 8
  for (int i = 0; i < 128; ++i) {
    float2 v = *(const float2*)(x + (size_t)(n0 + i) * HDIM + h0 + tid * 2);
    int s0 = sidx[2 * i] << 1;            // (e0, k=0)
    int s1 = (sidx[2 * i + 1] << 1) + 1;  // (e1, k=1)
    part[s0][tid].x += v.x; part[s0][tid].y += v.y;
    part[s1][tid].x += v.x; part[s1][tid].y += v.y;
  }
#pragma unroll
  for (int s = 0; s < 16; ++s) {
    atomicAdd(&tok[s * HDIM + h0 + tid * 2 + 0], part[s][tid].x);
    atomicAdd(&tok[s * HDIM + h0 + tid * 2 + 1], part[s][tid].y);
  }
}

// ---- up-proj, row-streaming: block = (e, 32 h-rows), streams 1 MB contiguous ----
// thread owns 8 f-float4 columns (f4 = j*256+tid); up_part[e][hc][k][f], hc<64.
__global__ __launch_bounds__(256) void up_kernel(const float* __restrict__ tok,
                                                 const float* __restrict__ W1,
                                                 float* __restrict__ up_part) {
  const int e = blockIdx.y;
  const int hc = blockIdx.x;          // 0..63
  const int tid = threadIdx.x;
  const int h0 = hc << 5;             // 32 rows
  __shared__ float ts[2][32];
  if (tid < 32)       ts[0][tid] = tok[(e * 2 + 0) * HDIM + h0 + tid];
  else if (tid < 64)  ts[1][tid - 32] = tok[(e * 2 + 1) * HDIM + h0 + (tid - 32)];
  __syncthreads();

  float4 a0[8], a1[8];
#pragma unroll
  for (int j = 0; j < 8; ++j) {
    a0[j] = make_float4(0.f, 0.f, 0.f, 0.f);
    a1[j] = make_float4(0.f, 0.f, 0.f, 0.f);
  }
  const float* base = W1 + ((size_t)e * HDIM + h0) * FDIM;
#pragma unroll 2
  for (int h = 0; h < 32; ++h) {
    const float* row = base + (size_t)h * FDIM;
    const float t0 = ts[0][h], t1 = ts[1][h];
#pragma unroll
    for (int j = 0; j < 8; ++j) {
      f32x4 w = __builtin_nontemporal_load(
          reinterpret_cast<const f32x4*>(row + ((j << 8) + tid) * 4));
      a0[j].x = fmaf(t0, w.x, a0[j].x); a0[j].y = fmaf(t0, w.y, a0[j].y);
      a0[j].z = fmaf(t0, w.z, a0[j].z); a0[j].w = fmaf(t0, w.w, a0[j].w);
      a1[j].x = fmaf(t1, w.x, a1[j].x); a1[j].y = fmaf(t1, w.y, a1[j].y);
      a1[j].z = fmaf(t1, w.z, a1[j].z); a1[j].w = fmaf(t1, w.w, a1[j].w);
    }
  }
  float* p0 = up_part + (size_t)((e * 64 + hc) * 2 + 0) * FDIM;
  float* p1 = up_part + (size_t)((e * 64 + hc) * 2 + 1) * FDIM;
#pragma unroll
  for (int j = 0; j < 8; ++j) {
    *(float4*)(p0 + ((j << 8) + tid) * 4) = a0[j];
    *(float4*)(p1 + ((j << 8) + tid) * 4) = a1[j];
  }
}

// ---- down-proj, row-streaming, fused gelu-reduce prologue ----
// block = (e, 128 f-rows), streams 1 MB contiguous; thread owns 2 h-float4 columns.
// down_part[e][fc][k][h], fc<64.
__global__ __launch_bounds__(256) void down_kernel(const float* __restrict__ up_part,
                                                   const float* __restrict__ b1,
                                                   const float* __restrict__ W2,
                                                   float* __restrict__ down_part) {
  const int e = blockIdx.y;
  const int fc = blockIdx.x;          // 0..63
  const int tid = threadIdx.x;
  const int f0 = fc << 7;             // 128 f-rows per block
  __shared__ float ms[2][128];
  {
    const int k = tid >> 7;           // 0 or 1
    const int fl = tid & 127;
    float acc = 0.f;
#pragma unroll
    for (int hc = 0; hc < 64; ++hc)
      acc += up_part[(size_t)((e * 64 + hc) * 2 + k) * FDIM + f0 + fl];
    acc += b1[e * FDIM + f0 + fl];
    ms[k][fl] = 0.5f * acc * (1.f + erff(acc * 0.70710678118654752f));
  }
  __syncthreads();

  float4 a[2][2];  // [k][j]  (j: h4 = j*256+tid)
#pragma unroll
  for (int k = 0; k < 2; ++k)
#pragma unroll
    for (int j = 0; j < 2; ++j) a[k][j] = make_float4(0.f, 0.f, 0.f, 0.f);
  const float* base = W2 + ((size_t)e * FDIM + f0) * HDIM;
#pragma unroll 8
  for (int ff = 0; ff < 128; ++ff) {
    const float* row = base + (size_t)ff * HDIM;
    const float m0 = ms[0][ff], m1 = ms[1][ff];
#pragma unroll
    for (int j = 0; j < 2; ++j) {
      f32x4 w = __builtin_nontemporal_load(
          reinterpret_cast<const f32x4*>(row + ((j << 8) + tid) * 4));
      a[0][j].x = fmaf(m0, w.x, a[0][j].x); a[0][j].y = fmaf(m0, w.y, a[0][j].y);
      a[0][j].z = fmaf(m0, w.z, a[0][j].z); a[0][j].w = fmaf(m0, w.w, a[0][j].w);
      a[1][j].x = fmaf(m1, w.x, a[1][j].x); a[1][j].y = fmaf(m1, w.y, a[1][j].y);
      a[1][j].z = fmaf(m1, w.z, a[1][j].z); a[1][j].w = fmaf(m1, w.w, a[1][j].w);
    }
  }
#pragma unroll
  for (int k = 0; k < 2; ++k) {
    float* p = down_part + (size_t)((e * 64 + fc) * 2 + k) * HDIM;
#pragma unroll
    for (int j = 0; j < 2; ++j) *(float4*)(p + ((j << 8) + tid) * 4) = a[k][j];
  }
}

// ---- ebar += coalesced reduction of down_part (512 slices); 64 blocks x 8 combos ----
__global__ __launch_bounds__(256) void ebar_reduce_kernel(const float* __restrict__ down_part,
                                                          float* __restrict__ ebar) {
  const int tid = threadIdx.x;
  const int c0 = blockIdx.x * 8;  // combos c = (e*64+fc) in [0,512)
  float4 acc[2][2];               // [k][h-round: h4 = tid, tid+256]
#pragma unroll
  for (int k = 0; k < 2; ++k)
#pragma unroll
    for (int r = 0; r < 2; ++r) acc[k][r] = make_float4(0.f, 0.f, 0.f, 0.f);
#pragma unroll
  for (int j = 0; j < 8; ++j) {
    const int c = c0 + j;
#pragma unroll
    for (int k = 0; k < 2; ++k) {
      const float* base = down_part + (size_t)(c * 2 + k) * HDIM;
#pragma unroll
      for (int r = 0; r < 2; ++r) {
        float4 v = *(const float4*)(base + ((r << 8) + tid) * 4);
        acc[k][r].x += v.x; acc[k][r].y += v.y; acc[k][r].z += v.z; acc[k][r].w += v.w;
      }
    }
  }
#pragma unroll
  for (int k = 0; k < 2; ++k)
#pragma unroll
    for (int r = 0; r < 2; ++r) {
      float* dst = ebar + k * HDIM + ((r << 8) + tid) * 4;
      atomicAdd(dst + 0, acc[k][r].x);
      atomicAdd(dst + 1, acc[k][r].y);
      atomicAdd(dst + 2, acc[k][r].z);
      atomicAdd(dst + 3, acc[k][r].w);
    }
}

// ---- combine: y[n,h] = G[n,0]*ebar[0,h] + G[n,1]*ebar[1,h] ----
__global__ __launch_bounds__(256) void combine_kernel(const float* __restrict__ G,
                                                      const float* __restrict__ ebar,
                                                      float* __restrict__ y) {
  const int i4 = blockIdx.x * 256 + threadIdx.x;  // NTOK*HDIM/4 = 4194304 total
  const int n = i4 >> 9;
  const int h = (i4 & 511) << 2;
  const float g0 = G[n * 2 + 0], g1 = G[n * 2 + 1];
  float4 e0 = *(const float4*)(ebar + h);
  float4 e1 = *(const float4*)(ebar + HDIM + h);
  f32x4 r;
  r.x = fmaf(g0, e0.x, g1 * e1.x);
  r.y = fmaf(g0, e0.y, g1 * e1.y);
  r.z = fmaf(g0, e0.z, g1 * e1.z);
  r.w = fmaf(g0, e0.w, g1 * e1.w);
  __builtin_nontemporal_store(r, reinterpret_cast<f32x4*>(y + ((size_t)n << 11) + h));
}

extern "C" void kernel_launch(void* const* d_in, const int* in_sizes, int n_in,
                              void* d_out, int out_size, void* d_ws, size_t ws_size,
                              hipStream_t stream) {
  const float* x  = (const float*)d_in[0];
  const float* Wr = (const float*)d_in[1];
  const float* br = (const float*)d_in[2];
  const float* W1 = (const float*)d_in[3];
  const float* b1 = (const float*)d_in[4];
  const float* W2 = (const float*)d_in[5];
  const float* b2 = (const float*)d_in[6];
  float* y = (float*)d_out;

  char* ws = (char*)d_ws;
  float* G         = (float*)(ws);               // 64 KB
  int*   sel       = (int*)(ws + (64 << 10));    // 64 KB
  float* tok       = (float*)(ws + (128 << 10)); // 128 KB
  float* ebar      = (float*)(ws + (256 << 10)); // 16 KB
  float* up_part   = (float*)(ws + (512 << 10));              // 32 MB: [8][64][2][8192]
  float* down_part = (float*)(ws + (512 << 10) + (32 << 20)); // 4 MB:  [8][64][2][2048]

  router_kernel<<<512, 256, 0, stream>>>(x, Wr, br, b2, G, sel, tok, ebar);
  tok_kernel<<<dim3(4, 64), 256, 0, stream>>>(x, sel, tok);
  up_kernel<<<dim3(64, 8), 256, 0, stream>>>(tok, W1, up_part);
  down_kernel<<<dim3(64, 8), 256, 0, stream>>>(up_part, b1, W2, down_part);
  ebar_reduce_kernel<<<64, 256, 0, stream>>>(down_part, ebar);
  combine_kernel<<<16384, 256, 0, stream>>>(G, ebar, y);
}

// Round 7
// 251.162 us; speedup vs baseline: 1.0441x; 1.0301x over previous
//
#include <hip/hip_runtime.h>
#include <math.h>

#define NTOK 8192   // B*S = 4*2048
#define HDIM 2048
#define FDIM 8192
#define NEXP 8

typedef float f32x4 __attribute__((ext_vector_type(4)));

// ---- router: logits = x@Wr + br, softmax, top-2; also zeroes tok and seeds ebar ----
__global__ __launch_bounds__(256) void router_kernel(const float* __restrict__ x,
                                                     const float* __restrict__ Wr,
                                                     const float* __restrict__ br,
                                                     const float* __restrict__ b2,
                                                     float* __restrict__ G,
                                                     int* __restrict__ sel,
                                                     float* __restrict__ tok,
                                                     float* __restrict__ ebar) {
  {
    const int idx = blockIdx.x * 256 + threadIdx.x;
    if (idx < (16 * HDIM) / 4) {
      *(float4*)(tok + idx * 4) = make_float4(0.f, 0.f, 0.f, 0.f);
    } else if (idx < (16 * HDIM) / 4 + 1024) {  // seed ebar[2][2048] with sum_e b2
      const int j = idx - (16 * HDIM) / 4;
      const int h = (j & 511) << 2;
      float4 s = make_float4(0.f, 0.f, 0.f, 0.f);
#pragma unroll
      for (int e = 0; e < 8; ++e) {
        float4 b = *(const float4*)(b2 + e * HDIM + h);
        s.x += b.x; s.y += b.y; s.z += b.z; s.w += b.w;
      }
      *(float4*)(ebar + (j >> 9) * HDIM + h) = s;
    }
  }
  const int wave = threadIdx.x >> 6;
  const int lane = threadIdx.x & 63;
  const int n0 = (blockIdx.x * 4 + wave) * 4;

  float acc[4][8];
#pragma unroll
  for (int t = 0; t < 4; ++t)
#pragma unroll
    for (int e = 0; e < 8; ++e) acc[t][e] = 0.f;

#pragma unroll 4
  for (int j = 0; j < 32; ++j) {
    const int h = lane + (j << 6);
    float4 wa = *(const float4*)(Wr + h * 8);
    float4 wb = *(const float4*)(Wr + h * 8 + 4);
    float w[8] = {wa.x, wa.y, wa.z, wa.w, wb.x, wb.y, wb.z, wb.w};
#pragma unroll
    for (int t = 0; t < 4; ++t) {
      float xv = x[(size_t)(n0 + t) * HDIM + h];
#pragma unroll
      for (int e = 0; e < 8; ++e) acc[t][e] = fmaf(xv, w[e], acc[t][e]);
    }
  }

#pragma unroll
  for (int t = 0; t < 4; ++t)
#pragma unroll
    for (int e = 0; e < 8; ++e) {
      float v = acc[t][e];
      v += __shfl_xor(v, 1, 64);
      v += __shfl_xor(v, 2, 64);
      v += __shfl_xor(v, 4, 64);
      v += __shfl_xor(v, 8, 64);
      v += __shfl_xor(v, 16, 64);
      v += __shfl_xor(v, 32, 64);
      acc[t][e] = v;
    }

  if (lane == 0) {
    float brv[8];
#pragma unroll
    for (int e = 0; e < 8; ++e) brv[e] = br[e];
#pragma unroll
    for (int t = 0; t < 4; ++t) {
      float l[8];
#pragma unroll
      for (int e = 0; e < 8; ++e) l[e] = acc[t][e] + brv[e];
      float m = l[0];
#pragma unroll
      for (int e = 1; e < 8; ++e) m = fmaxf(m, l[e]);
      float s = 0.f;
#pragma unroll
      for (int e = 0; e < 8; ++e) s += expf(l[e] - m);
      float best = l[0], second = -3.4e38f;
      int bi = 0, si = 0;
#pragma unroll
      for (int e = 1; e < 8; ++e) {
        float v = l[e];
        if (v > best) { second = best; si = bi; best = v; bi = e; }
        else if (v > second) { second = v; si = e; }
      }
      const int n = n0 + t;
      const float inv = 1.f / s;
      G[n * 2 + 0] = expf(best - m) * inv;
      G[n * 2 + 1] = expf(second - m) * inv;
      sel[n * 2 + 0] = bi;
      sel[n * 2 + 1] = si;
    }
  }
}

// ---- tok[e,k,h]: 512 blocks (8 h-chunks x 64 token-chunks), scalar loads ----
__global__ __launch_bounds__(256) void tok_kernel(const float* __restrict__ x,
                                                  const int* __restrict__ sel,
                                                  float* __restrict__ tok) {
  __shared__ float part[16][256];
  __shared__ int sidx[256];
  const int tid = threadIdx.x;
  const int h0 = blockIdx.x << 8;  // 8 chunks x 256 h
  const int n0 = blockIdx.y << 7;  // 64 chunks x 128 tokens
#pragma unroll
  for (int s = 0; s < 16; ++s) part[s][tid] = 0.f;
  sidx[tid] = sel[(n0 << 1) + tid];
  __syncthreads();
#pragma unroll 8
  for (int i = 0; i < 128; ++i) {
    float v = x[(size_t)(n0 + i) * HDIM + h0 + tid];
    int s0 = sidx[2 * i] << 1;            // (e0, k=0)
    int s1 = (sidx[2 * i + 1] << 1) + 1;  // (e1, k=1)
    part[s0][tid] += v;
    part[s1][tid] += v;
  }
#pragma unroll
  for (int s = 0; s < 16; ++s) atomicAdd(&tok[s * HDIM + h0 + tid], part[s][tid]);
}

// ---- up-proj: block = (e, f-half, 32 h-rows); 4 f4-acc/thread -> low VGPR, 4 blk/CU ----
// up_part[e][hc<64][k][f 8192]
__global__ __launch_bounds__(256) void up_kernel(const float* __restrict__ tok,
                                                 const float* __restrict__ W1,
                                                 float* __restrict__ up_part) {
  const int e = blockIdx.z;
  const int fh = blockIdx.y;          // 0..1 f-half
  const int hc = blockIdx.x;          // 0..63
  const int tid = threadIdx.x;
  const int h0 = hc << 5;             // 32 rows
  const int fbase = fh << 12;         // 4096 floats
  __shared__ float ts[2][32];
  if (tid < 32)       ts[0][tid] = tok[(e * 2 + 0) * HDIM + h0 + tid];
  else if (tid < 64)  ts[1][tid - 32] = tok[(e * 2 + 1) * HDIM + h0 + (tid - 32)];
  __syncthreads();

  float4 a0[4], a1[4];
#pragma unroll
  for (int j = 0; j < 4; ++j) {
    a0[j] = make_float4(0.f, 0.f, 0.f, 0.f);
    a1[j] = make_float4(0.f, 0.f, 0.f, 0.f);
  }
  const float* base = W1 + ((size_t)e * HDIM + h0) * FDIM + fbase;
#pragma unroll 2
  for (int h = 0; h < 32; ++h) {
    const float* row = base + (size_t)h * FDIM;
    const float t0 = ts[0][h], t1 = ts[1][h];
#pragma unroll
    for (int j = 0; j < 4; ++j) {
      f32x4 w = __builtin_nontemporal_load(
          reinterpret_cast<const f32x4*>(row + ((j << 8) + tid) * 4));
      a0[j].x = fmaf(t0, w.x, a0[j].x); a0[j].y = fmaf(t0, w.y, a0[j].y);
      a0[j].z = fmaf(t0, w.z, a0[j].z); a0[j].w = fmaf(t0, w.w, a0[j].w);
      a1[j].x = fmaf(t1, w.x, a1[j].x); a1[j].y = fmaf(t1, w.y, a1[j].y);
      a1[j].z = fmaf(t1, w.z, a1[j].z); a1[j].w = fmaf(t1, w.w, a1[j].w);
    }
  }
  float* p0 = up_part + (size_t)((e * 64 + hc) * 2 + 0) * FDIM + fbase;
  float* p1 = up_part + (size_t)((e * 64 + hc) * 2 + 1) * FDIM + fbase;
#pragma unroll
  for (int j = 0; j < 4; ++j) {
    *(float4*)(p0 + ((j << 8) + tid) * 4) = a0[j];
    *(float4*)(p1 + ((j << 8) + tid) * 4) = a1[j];
  }
}

// ---- gelu-reduce: mid[ek][f] = gelu(sum_hc up_part + b1); 256 blocks x 128 thr ----
__global__ __launch_bounds__(128) void gelu_reduce_kernel(const float* __restrict__ up_part,
                                                          const float* __restrict__ b1,
                                                          float* __restrict__ mid) {
  const int i4 = blockIdx.x * 128 + threadIdx.x;  // 32768 total: 16*8192/4
  const int f = (i4 & (FDIM / 4 - 1)) << 2;
  const int ek = i4 >> 11;                        // 0..15
  const int e = ek >> 1;
  float4 s = make_float4(0.f, 0.f, 0.f, 0.f);
#pragma unroll 16
  for (int hc = 0; hc < 64; ++hc) {
    float4 v = *(const float4*)(up_part + (size_t)((e * 64 + hc) * 2 + (ek & 1)) * FDIM + f);
    s.x += v.x; s.y += v.y; s.z += v.z; s.w += v.w;
  }
  float4 b = *(const float4*)(b1 + e * FDIM + f);
  s.x += b.x; s.y += b.y; s.z += b.z; s.w += b.w;
  float4 r;
  r.x = 0.5f * s.x * (1.f + erff(s.x * 0.70710678118654752f));
  r.y = 0.5f * s.y * (1.f + erff(s.y * 0.70710678118654752f));
  r.z = 0.5f * s.z * (1.f + erff(s.z * 0.70710678118654752f));
  r.w = 0.5f * s.w * (1.f + erff(s.w * 0.70710678118654752f));
  *(float4*)(mid + (size_t)ek * FDIM + f) = r;
}

// ---- down-proj: block = (e, h-half, 128 f-rows); 2 f4-acc/thread ----
// down_part[e][fc<64][k][h 2048]
__global__ __launch_bounds__(256) void down_kernel(const float* __restrict__ mid,
                                                   const float* __restrict__ W2,
                                                   float* __restrict__ down_part) {
  const int e = blockIdx.z;
  const int hh = blockIdx.y;          // 0..1 h-half
  const int fc = blockIdx.x;          // 0..63
  const int tid = threadIdx.x;
  const int f0 = fc << 7;             // 128 f-rows
  const int hbase = hh << 10;         // 1024 floats
  __shared__ float ms[2][128];
  if (tid < 128) ms[0][tid] = mid[(e * 2 + 0) * FDIM + f0 + tid];
  else           ms[1][tid - 128] = mid[(e * 2 + 1) * FDIM + f0 + (tid - 128)];
  __syncthreads();

  float4 a0 = make_float4(0.f, 0.f, 0.f, 0.f), a1 = make_float4(0.f, 0.f, 0.f, 0.f);
  const float* base = W2 + ((size_t)e * FDIM + f0) * HDIM + hbase + tid * 4;
#pragma unroll 8
  for (int ff = 0; ff < 128; ++ff) {
    f32x4 w = __builtin_nontemporal_load(
        reinterpret_cast<const f32x4*>(base + (size_t)ff * HDIM));
    const float m0 = ms[0][ff], m1 = ms[1][ff];
    a0.x = fmaf(m0, w.x, a0.x); a0.y = fmaf(m0, w.y, a0.y);
    a0.z = fmaf(m0, w.z, a0.z); a0.w = fmaf(m0, w.w, a0.w);
    a1.x = fmaf(m1, w.x, a1.x); a1.y = fmaf(m1, w.y, a1.y);
    a1.z = fmaf(m1, w.z, a1.z); a1.w = fmaf(m1, w.w, a1.w);
  }
  float* p0 = down_part + (size_t)((e * 64 + fc) * 2 + 0) * HDIM + hbase + tid * 4;
  float* p1 = down_part + (size_t)((e * 64 + fc) * 2 + 1) * HDIM + hbase + tid * 4;
  *(float4*)p0 = a0;
  *(float4*)p1 = a1;
}

// ---- ebar += coalesced reduction of down_part (512 slices); 64 blocks x 8 combos ----
__global__ __launch_bounds__(256) void ebar_reduce_kernel(const float* __restrict__ down_part,
                                                          float* __restrict__ ebar) {
  const int tid = threadIdx.x;
  const int c0 = blockIdx.x * 8;  // combos c = (e*64+fc) in [0,512)
  float4 acc[2][2];               // [k][h-round: h4 = tid, tid+256]
#pragma unroll
  for (int k = 0; k < 2; ++k)
#pragma unroll
    for (int r = 0; r < 2; ++r) acc[k][r] = make_float4(0.f, 0.f, 0.f, 0.f);
#pragma unroll
  for (int j = 0; j < 8; ++j) {
    const int c = c0 + j;
#pragma unroll
    for (int k = 0; k < 2; ++k) {
      const float* base = down_part + (size_t)(c * 2 + k) * HDIM;
#pragma unroll
      for (int r = 0; r < 2; ++r) {
        float4 v = *(const float4*)(base + ((r << 8) + tid) * 4);
        acc[k][r].x += v.x; acc[k][r].y += v.y; acc[k][r].z += v.z; acc[k][r].w += v.w;
      }
    }
  }
#pragma unroll
  for (int k = 0; k < 2; ++k)
#pragma unroll
    for (int r = 0; r < 2; ++r) {
      float* dst = ebar + k * HDIM + ((r << 8) + tid) * 4;
      atomicAdd(dst + 0, acc[k][r].x);
      atomicAdd(dst + 1, acc[k][r].y);
      atomicAdd(dst + 2, acc[k][r].z);
      atomicAdd(dst + 3, acc[k][r].w);
    }
}

// ---- combine: y[n,h] = G[n,0]*ebar[0,h] + G[n,1]*ebar[1,h] ----
__global__ __launch_bounds__(256) void combine_kernel(const float* __restrict__ G,
                                                      const float* __restrict__ ebar,
                                                      float* __restrict__ y) {
  const int i4 = blockIdx.x * 256 + threadIdx.x;  // NTOK*HDIM/4 = 4194304 total
  const int n = i4 >> 9;
  const int h = (i4 & 511) << 2;
  const float g0 = G[n * 2 + 0], g1 = G[n * 2 + 1];
  float4 e0 = *(const float4*)(ebar + h);
  float4 e1 = *(const float4*)(ebar + HDIM + h);
  f32x4 r;
  r.x = fmaf(g0, e0.x, g1 * e1.x);
  r.y = fmaf(g0, e0.y, g1 * e1.y);
  r.z = fmaf(g0, e0.z, g1 * e1.z);
  r.w = fmaf(g0, e0.w, g1 * e1.w);
  __builtin_nontemporal_store(r, reinterpret_cast<f32x4*>(y + ((size_t)n << 11) + h));
}

extern "C" void kernel_launch(void* const* d_in, const int* in_sizes, int n_in,
                              void* d_out, int out_size, void* d_ws, size_t ws_size,
                              hipStream_t stream) {
  const float* x  = (const float*)d_in[0];
  const float* Wr = (const float*)d_in[1];
  const float* br = (const float*)d_in[2];
  const float* W1 = (const float*)d_in[3];
  const float* b1 = (const float*)d_in[4];
  const float* W2 = (const float*)d_in[5];
  const float* b2 = (const float*)d_in[6];
  float* y = (float*)d_out;

  char* ws = (char*)d_ws;
  float* G         = (float*)(ws);               // 64 KB
  int*   sel       = (int*)(ws + (64 << 10));    // 64 KB
  float* tok       = (float*)(ws + (128 << 10)); // 128 KB
  float* ebar      = (float*)(ws + (256 << 10)); // 16 KB
  float* mid       = (float*)(ws + (320 << 10)); // 512 KB
  float* up_part   = (float*)(ws + (1 << 20));             // 32 MB: [8][64][2][8192]
  float* down_part = (float*)(ws + (1 << 20) + (32 << 20)); // 4 MB: [8][64][2][2048]

  router_kernel<<<512, 256, 0, stream>>>(x, Wr, br, b2, G, sel, tok, ebar);
  tok_kernel<<<dim3(8, 64), 256, 0, stream>>>(x, sel, tok);
  up_kernel<<<dim3(64, 2, 8), 256, 0, stream>>>(tok, W1, up_part);
  gelu_reduce_kernel<<<256, 128, 0, stream>>>(up_part, b1, mid);
  down_kernel<<<dim3(64, 2, 8), 256, 0, stream>>>(mid, W2, down_part);
  ebar_reduce_kernel<<<64, 256, 0, stream>>>(down_part, ebar);
  combine_kernel<<<16384, 256, 0, stream>>>(G, ebar, y);
}

// Round 8
// 229.681 us; speedup vs baseline: 1.1417x; 1.0935x over previous
//
#include <hip/hip_runtime.h>
#include <math.h>

#define NTOK 8192   // B*S = 4*2048
#define HDIM 2048
#define FDIM 8192
#define NEXP 8

typedef float f32x4 __attribute__((ext_vector_type(4)));

__device__ __forceinline__ f32x4 nt_load4(const float* p) {
  return __builtin_nontemporal_load(reinterpret_cast<const f32x4*>(p));
}

// ---- router: logits = x@Wr + br, softmax, top-2; also zeroes tok and seeds ebar ----
__global__ __launch_bounds__(256) void router_kernel(const float* __restrict__ x,
                                                     const float* __restrict__ Wr,
                                                     const float* __restrict__ br,
                                                     const float* __restrict__ b2,
                                                     float* __restrict__ G,
                                                     int* __restrict__ sel,
                                                     float* __restrict__ tok,
                                                     float* __restrict__ ebar) {
  {
    const int idx = blockIdx.x * 256 + threadIdx.x;
    if (idx < (16 * HDIM) / 4) {
      *(float4*)(tok + idx * 4) = make_float4(0.f, 0.f, 0.f, 0.f);
    } else if (idx < (16 * HDIM) / 4 + 1024) {  // seed ebar[2][2048] with sum_e b2
      const int j = idx - (16 * HDIM) / 4;
      const int h = (j & 511) << 2;
      float4 s = make_float4(0.f, 0.f, 0.f, 0.f);
#pragma unroll
      for (int e = 0; e < 8; ++e) {
        float4 b = *(const float4*)(b2 + e * HDIM + h);
        s.x += b.x; s.y += b.y; s.z += b.z; s.w += b.w;
      }
      *(float4*)(ebar + (j >> 9) * HDIM + h) = s;
    }
  }
  const int wave = threadIdx.x >> 6;
  const int lane = threadIdx.x & 63;
  const int n0 = (blockIdx.x * 4 + wave) * 4;

  float acc[4][8];
#pragma unroll
  for (int t = 0; t < 4; ++t)
#pragma unroll
    for (int e = 0; e < 8; ++e) acc[t][e] = 0.f;

#pragma unroll 4
  for (int j = 0; j < 32; ++j) {
    const int h = lane + (j << 6);
    float4 wa = *(const float4*)(Wr + h * 8);
    float4 wb = *(const float4*)(Wr + h * 8 + 4);
    float w[8] = {wa.x, wa.y, wa.z, wa.w, wb.x, wb.y, wb.z, wb.w};
#pragma unroll
    for (int t = 0; t < 4; ++t) {
      float xv = x[(size_t)(n0 + t) * HDIM + h];
#pragma unroll
      for (int e = 0; e < 8; ++e) acc[t][e] = fmaf(xv, w[e], acc[t][e]);
    }
  }

#pragma unroll
  for (int t = 0; t < 4; ++t)
#pragma unroll
    for (int e = 0; e < 8; ++e) {
      float v = acc[t][e];
      v += __shfl_xor(v, 1, 64);
      v += __shfl_xor(v, 2, 64);
      v += __shfl_xor(v, 4, 64);
      v += __shfl_xor(v, 8, 64);
      v += __shfl_xor(v, 16, 64);
      v += __shfl_xor(v, 32, 64);
      acc[t][e] = v;
    }

  if (lane == 0) {
    float brv[8];
#pragma unroll
    for (int e = 0; e < 8; ++e) brv[e] = br[e];
#pragma unroll
    for (int t = 0; t < 4; ++t) {
      float l[8];
#pragma unroll
      for (int e = 0; e < 8; ++e) l[e] = acc[t][e] + brv[e];
      float m = l[0];
#pragma unroll
      for (int e = 1; e < 8; ++e) m = fmaxf(m, l[e]);
      float s = 0.f;
#pragma unroll
      for (int e = 0; e < 8; ++e) s += expf(l[e] - m);
      float best = l[0], second = -3.4e38f;
      int bi = 0, si = 0;
#pragma unroll
      for (int e = 1; e < 8; ++e) {
        float v = l[e];
        if (v > best) { second = best; si = bi; best = v; bi = e; }
        else if (v > second) { second = v; si = e; }
      }
      const int n = n0 + t;
      const float inv = 1.f / s;
      G[n * 2 + 0] = expf(best - m) * inv;
      G[n * 2 + 1] = expf(second - m) * inv;
      sel[n * 2 + 0] = bi;
      sel[n * 2 + 1] = si;
    }
  }
}

// ---- tok[e,k,h]: 512 blocks (8 h-chunks x 64 token-chunks) ----
__global__ __launch_bounds__(256) void tok_kernel(const float* __restrict__ x,
                                                  const int* __restrict__ sel,
                                                  float* __restrict__ tok) {
  __shared__ float part[16][256];
  __shared__ int sidx[256];
  const int tid = threadIdx.x;
  const int h0 = blockIdx.x << 8;  // 8 chunks x 256 h
  const int n0 = blockIdx.y << 7;  // 64 chunks x 128 tokens
#pragma unroll
  for (int s = 0; s < 16; ++s) part[s][tid] = 0.f;
  sidx[tid] = sel[(n0 << 1) + tid];
  __syncthreads();
#pragma unroll 8
  for (int i = 0; i < 128; ++i) {
    float v = x[(size_t)(n0 + i) * HDIM + h0 + tid];
    int s0 = sidx[2 * i] << 1;            // (e0, k=0)
    int s1 = (sidx[2 * i + 1] << 1) + 1;  // (e1, k=1)
    part[s0][tid] += v;
    part[s1][tid] += v;
  }
#pragma unroll
  for (int s = 0; s < 16; ++s) atomicAdd(&tok[s * HDIM + h0 + tid], part[s][tid]);
}

// ---- fused expert FFN: block = (e, 256-f column slice); 256 blocks, 1/CU ----
// phase 1: mid[k][256] = gelu(sum_h tok[e,k,h] * W1[e,h,f0+0..255] + b1)  (in LDS)
// phase 2: down_part[e][sl][k][0..2047] = sum_ff mid[k][ff] * W2[e,f0+ff,:]
__global__ __launch_bounds__(256) void ffn_kernel(const float* __restrict__ tok,
                                                  const float* __restrict__ W1,
                                                  const float* __restrict__ b1,
                                                  const float* __restrict__ W2,
                                                  float* __restrict__ down_part) {
  const int e = blockIdx.y;
  const int sl = blockIdx.x;       // 0..31
  const int tid = threadIdx.x;
  const int f0 = sl << 8;          // 256 f per slice

  __shared__ f32x4 tok_s[1024];    // [2][2048] floats = 16 KB
  __shared__ f32x4 red[2][4][64];  // 8 KB
  __shared__ f32x4 ms4[2][64];     // mid, 2 KB

  // cooperative load of tok[e][0..1][:] into LDS
  {
    const f32x4* src = reinterpret_cast<const f32x4*>(tok + (size_t)(e * 2) * HDIM);
#pragma unroll
    for (int j = 0; j < 4; ++j) tok_s[j * 256 + tid] = src[j * 256 + tid];
  }
  __syncthreads();
  const float* tok_f = reinterpret_cast<const float*>(tok_s);

  // ---- phase 1: W1 column slice, wave-load = 1 KB contiguous ----
  const int fq = tid & 63;         // f-float4 within slice
  const int hq = tid >> 6;         // row phase 0..3
  f32x4 a0 = {0.f, 0.f, 0.f, 0.f}, a1 = {0.f, 0.f, 0.f, 0.f};
  const float* base1 = W1 + (size_t)e * HDIM * FDIM + f0 + (fq << 2);
#pragma unroll 8
  for (int i = 0; i < 512; ++i) {
    const int h = hq + (i << 2);
    f32x4 w = nt_load4(base1 + (size_t)h * FDIM);
    const float t0 = tok_f[h];
    const float t1 = tok_f[2048 + h];
    a0 += t0 * w;
    a1 += t1 * w;
  }
  red[0][hq][fq] = a0;
  red[1][hq][fq] = a1;
  __syncthreads();
  if (tid < 128) {
    const int k = tid >> 6, f = tid & 63;
    f32x4 s = red[k][0][f] + red[k][1][f] + red[k][2][f] + red[k][3][f];
    s += *reinterpret_cast<const f32x4*>(b1 + e * FDIM + f0 + (f << 2));
    f32x4 r;
    r.x = 0.5f * s.x * (1.f + erff(s.x * 0.70710678118654752f));
    r.y = 0.5f * s.y * (1.f + erff(s.y * 0.70710678118654752f));
    r.z = 0.5f * s.z * (1.f + erff(s.z * 0.70710678118654752f));
    r.w = 0.5f * s.w * (1.f + erff(s.w * 0.70710678118654752f));
    ms4[k][f] = r;
  }
  __syncthreads();
  const float* ms = reinterpret_cast<const float*>(ms4);  // [2][256]

  // ---- phase 2: W2 row slice, 2 MB fully contiguous ----
  f32x4 c00 = {0.f, 0.f, 0.f, 0.f}, c01 = {0.f, 0.f, 0.f, 0.f};
  f32x4 c10 = {0.f, 0.f, 0.f, 0.f}, c11 = {0.f, 0.f, 0.f, 0.f};
  const float* base2 = W2 + (size_t)(e * FDIM + f0) * HDIM + (tid << 2);
#pragma unroll 8
  for (int ff = 0; ff < 256; ++ff) {
    const float* row = base2 + (size_t)ff * HDIM;
    const float m0 = ms[ff];
    const float m1 = ms[256 + ff];
    f32x4 w0 = nt_load4(row);         // h = tid*4
    f32x4 w1 = nt_load4(row + 1024);  // h = tid*4 + 1024
    c00 += m0 * w0; c01 += m0 * w1;
    c10 += m1 * w0; c11 += m1 * w1;
  }
  float* p0 = down_part + (size_t)((e * 32 + sl) * 2 + 0) * HDIM + (tid << 2);
  float* p1 = down_part + (size_t)((e * 32 + sl) * 2 + 1) * HDIM + (tid << 2);
  *reinterpret_cast<f32x4*>(p0) = c00;
  *reinterpret_cast<f32x4*>(p0 + 1024) = c01;
  *reinterpret_cast<f32x4*>(p1) = c10;
  *reinterpret_cast<f32x4*>(p1 + 1024) = c11;
}

// ---- ebar += reduction of down_part (256 slices); 64 blocks x 4 combos ----
__global__ __launch_bounds__(256) void ebar_reduce_kernel(const float* __restrict__ down_part,
                                                          float* __restrict__ ebar) {
  const int tid = threadIdx.x;
  const int c0 = blockIdx.x * 4;  // combos c = (e*32+sl) in [0,256)
  float4 acc[2][2];               // [k][h-round: h4 = tid, tid+256]
#pragma unroll
  for (int k = 0; k < 2; ++k)
#pragma unroll
    for (int r = 0; r < 2; ++r) acc[k][r] = make_float4(0.f, 0.f, 0.f, 0.f);
#pragma unroll
  for (int j = 0; j < 4; ++j) {
    const int c = c0 + j;
#pragma unroll
    for (int k = 0; k < 2; ++k) {
      const float* base = down_part + (size_t)(c * 2 + k) * HDIM;
#pragma unroll
      for (int r = 0; r < 2; ++r) {
        float4 v = *(const float4*)(base + ((r << 8) + tid) * 4);
        acc[k][r].x += v.x; acc[k][r].y += v.y; acc[k][r].z += v.z; acc[k][r].w += v.w;
      }
    }
  }
#pragma unroll
  for (int k = 0; k < 2; ++k)
#pragma unroll
    for (int r = 0; r < 2; ++r) {
      float* dst = ebar + k * HDIM + ((r << 8) + tid) * 4;
      atomicAdd(dst + 0, acc[k][r].x);
      atomicAdd(dst + 1, acc[k][r].y);
      atomicAdd(dst + 2, acc[k][r].z);
      atomicAdd(dst + 3, acc[k][r].w);
    }
}

// ---- combine: y[n,h] = G[n,0]*ebar[0,h] + G[n,1]*ebar[1,h] ----
__global__ __launch_bounds__(256) void combine_kernel(const float* __restrict__ G,
                                                      const float* __restrict__ ebar,
                                                      float* __restrict__ y) {
  const int i4 = blockIdx.x * 256 + threadIdx.x;  // NTOK*HDIM/4 = 4194304 total
  const int n = i4 >> 9;
  const int h = (i4 & 511) << 2;
  const float g0 = G[n * 2 + 0], g1 = G[n * 2 + 1];
  float4 e0 = *(const float4*)(ebar + h);
  float4 e1 = *(const float4*)(ebar + HDIM + h);
  f32x4 r;
  r.x = fmaf(g0, e0.x, g1 * e1.x);
  r.y = fmaf(g0, e0.y, g1 * e1.y);
  r.z = fmaf(g0, e0.z, g1 * e1.z);
  r.w = fmaf(g0, e0.w, g1 * e1.w);
  __builtin_nontemporal_store(r, reinterpret_cast<f32x4*>(y + ((size_t)n << 11) + h));
}

extern "C" void kernel_launch(void* const* d_in, const int* in_sizes, int n_in,
                              void* d_out, int out_size, void* d_ws, size_t ws_size,
                              hipStream_t stream) {
  const float* x  = (const float*)d_in[0];
  const float* Wr = (const float*)d_in[1];
  const float* br = (const float*)d_in[2];
  const float* W1 = (const float*)d_in[3];
  const float* b1 = (const float*)d_in[4];
  const float* W2 = (const float*)d_in[5];
  const float* b2 = (const float*)d_in[6];
  float* y = (float*)d_out;

  char* ws = (char*)d_ws;
  float* G         = (float*)(ws);               // 64 KB
  int*   sel       = (int*)(ws + (64 << 10));    // 64 KB
  float* tok       = (float*)(ws + (128 << 10)); // 128 KB
  float* ebar      = (float*)(ws + (256 << 10)); // 16 KB
  float* down_part = (float*)(ws + (512 << 10)); // 4 MB: [8][32][2][2048]

  router_kernel<<<512, 256, 0, stream>>>(x, Wr, br, b2, G, sel, tok, ebar);
  tok_kernel<<<dim3(8, 64), 256, 0, stream>>>(x, sel, tok);
  ffn_kernel<<<dim3(32, 8), 256, 0, stream>>>(tok, W1, b1, W2, down_part);
  ebar_reduce_kernel<<<64, 256, 0, stream>>>(down_part, ebar);
  combine_kernel<<<16384, 256, 0, stream>>>(G, ebar, y);
}